// Round 14
// baseline (736.105 us; speedup 1.0000x reference)
//
#include <hip/hip_runtime.h>
#include <cstdint>
#include <cstddef>

#define NND   128
#define FEATD 1024
#define MSGD  256
#define LHD   512
#define CLSD  600
#define LDST  264   // padded LDS row stride (528B, 16B-aligned)

typedef __bf16 bf16_t;
typedef bf16_t bf16x8 __attribute__((ext_vector_type(8)));
typedef float  f32x4  __attribute__((ext_vector_type(4)));
typedef unsigned short u16;
typedef u16 u16x8 __attribute__((ext_vector_type(8)));
typedef u16 u16x4 __attribute__((ext_vector_type(4)));

static __device__ __forceinline__ float bf2f(u16 u) {
  union { unsigned u; float f; } x; x.u = ((unsigned)u) << 16; return x.f;
}
static __device__ __forceinline__ u16 f2bf(float f) {
  union { float f; unsigned u; } x; x.f = f;
  return (u16)((x.u + 0x7fffu + ((x.u >> 16) & 1u)) >> 16);  // RNE
}
static __device__ __forceinline__ f32x4 mfma16(u16x8 a, u16x8 b, f32x4 c) {
  return __builtin_amdgcn_mfma_f32_16x16x32_bf16(
      __builtin_bit_cast(bf16x8, a), __builtin_bit_cast(bf16x8, b), c, 0, 0, 0);
}
static __device__ __forceinline__ f32x4 zero4() {
  f32x4 v; v[0] = 0.f; v[1] = 0.f; v[2] = 0.f; v[3] = 0.f; return v;
}
static __device__ __forceinline__ float sigm(float x) { return 1.0f / (1.0f + expf(-x)); }

// ---------------------------------------------------------------- weight cvt f32->bf16
__global__ void k_cvt(const float* __restrict__ src, u16* __restrict__ dst, int n) {
  int i = (blockIdx.x * 256 + threadIdx.x) * 4;
  if (i + 3 < n) {
    float4 f = *(const float4*)(src + i);
    u16x4 o; o[0] = f2bf(f.x); o[1] = f2bf(f.y); o[2] = f2bf(f.z); o[3] = f2bf(f.w);
    *(u16x4*)(dst + i) = o;
  }
}

// ---------------------------------------------------------------- W_comb (tier2 fallback only)
__global__ __launch_bounds__(256) void k_comb(const float* __restrict__ Wm,
                                              const float* __restrict__ Wer,
                                              const float* __restrict__ b_er,
                                              const float* __restrict__ b_m,
                                              u16* __restrict__ WcombB,
                                              float* __restrict__ bcomb) {
  const int m = blockIdx.x >> 2, ch = blockIdx.x & 3;
  const int d = ch * 256 + threadIdx.x;
  float s = 0.f;
  for (int k = 0; k < 256; ++k)
    s += Wm[(size_t)m * 512 + 256 + k] * Wer[(size_t)k * FEATD + d];
  WcombB[(size_t)m * FEATD + d] = f2bf(s);
  if (ch == 0 && threadIdx.x == 0) {
    float bb2 = b_m[m];
    for (int k = 0; k < 256; ++k) bb2 += Wm[(size_t)m * 512 + 256 + k] * b_er[k];
    bcomb[m] = bb2;
  }
}

// ---------------------------------------------------------------- S1: h (f32) + msg_h (bf16)
__global__ __launch_bounds__(256) void s1_hmsg(const float* __restrict__ node,
                                               const float* __restrict__ Wnr,
                                               const float* __restrict__ bnr,
                                               const float* __restrict__ Wm,
                                               float* __restrict__ h32,
                                               u16* __restrict__ msghB) {
  __shared__ float nrow[FEATD];
  __shared__ float hrow[MSGD];
  const int r = blockIdx.x;
  const int t = threadIdx.x;
  *(float4*)(&nrow[t * 4]) = *(const float4*)(node + (size_t)r * FEATD + t * 4);
  __syncthreads();
  float acc = bnr[t];
  for (int d = 0; d < FEATD; ++d) acc += nrow[d] * Wnr[(size_t)t * FEATD + d];
  h32[(size_t)r * MSGD + t] = acc;
  hrow[t] = acc;
  __syncthreads();
  float mh = 0.f;
  for (int k = 0; k < MSGD; ++k) mh += hrow[k] * Wm[(size_t)t * 2 * MSGD + k];
  msghB[(size_t)r * MSGD + t] = f2bf(mh);
}

// ---------------------------------------------------------------- main monolith
// Register-budget target: R13 showed VGPR 204 (+64 acc) = 268 > 256 -> 1 wave/SIMD;
// R11 showed 128 (+64) = 192 -> 2 waves but ~70 regs spilled (HBM round-trips).
// This version shaves the phase-0 B double-buffer (32->16 regs) targeting <=192 VGPR
// so BOTH no-spill and 2 waves/SIMD hold. (256,1) keeps the allocator uncapped.
__global__ __launch_bounds__(256, 1) void k_main_full(
    const float* __restrict__ edge, const u16* __restrict__ Wer, const u16* __restrict__ Wm,
    const u16* __restrict__ Wl1, const float* __restrict__ b_er, const float* __restrict__ b_m,
    const float* __restrict__ b_l1, const float* __restrict__ W_l2, const float* __restrict__ b_l2,
    const u16* __restrict__ msgh, u16* __restrict__ M0g, float* __restrict__ pa_out) {
  __shared__ __align__(16) u16 lsE[64][LDST];
  __shared__ __align__(16) u16 lsM[64][LDST];
  __shared__ float lsPA[4][64];
  __shared__ float lsSig[64];

  const int tid = threadIdx.x, lane = tid & 63, wave = tid >> 6;
  const int lh = lane & 15, lq = lane >> 4;
  const int base = blockIdx.x * 64;
  const int bb = base >> 14, vv = (base >> 7) & 127, w0 = base & 127;

  f32x4 acc[4][4];
#pragma unroll
  for (int m = 0; m < 4; ++m)
#pragma unroll
    for (int t = 0; t < 4; ++t) acc[m][t] = zero4();

  // ---------------- Phase 0: 16 K-steps of BK=64; single-buffer B (bst[4]) ----------------
  const int srow = tid >> 2;
  const int scq  = (tid & 3) * 16;
  const float* esrc = edge + (size_t)(base + srow) * FEATD + scq;
  float4 lda[4], ldb[4];
  u16x8 bst[4];   // one ks-half of B fragments (16 VGPRs; was 32)

  auto LOADS_A = [&](int s) {
#pragma unroll
    for (int i = 0; i < 4; ++i) lda[i] = *(const float4*)(esrc + s * 64 + i * 4);
  };
  auto LOADS_B = [&](int s) {
#pragma unroll
    for (int i = 0; i < 4; ++i) ldb[i] = *(const float4*)(esrc + s * 64 + i * 4);
  };
  auto WRITES = [&](const float4* ld, int slot) {
    u16* wp = &lsE[srow][slot * 64 + scq];
    u16x8 o0, o1;
    o0[0] = f2bf(ld[0].x); o0[1] = f2bf(ld[0].y); o0[2] = f2bf(ld[0].z); o0[3] = f2bf(ld[0].w);
    o0[4] = f2bf(ld[1].x); o0[5] = f2bf(ld[1].y); o0[6] = f2bf(ld[1].z); o0[7] = f2bf(ld[1].w);
    o1[0] = f2bf(ld[2].x); o1[1] = f2bf(ld[2].y); o1[2] = f2bf(ld[2].z); o1[3] = f2bf(ld[2].w);
    o1[4] = f2bf(ld[3].x); o1[5] = f2bf(ld[3].y); o1[6] = f2bf(ld[3].z); o1[7] = f2bf(ld[3].w);
    *(u16x8*)wp = o0;
    *(u16x8*)(wp + 8) = o1;
  };
  auto BLOAD = [&](int sk, int ks) {
#pragma unroll
    for (int t = 0; t < 4; ++t) {
      int col = wave * 64 + t * 16 + lh;
      bst[t] = *(const u16x8*)(Wer + (size_t)col * FEATD + sk * 64 + ks * 32 + lq * 8);
    }
  };
  auto MCOMP1 = [&](int slot, int ks) {   // one ks-half: 4 ds_reads + 16 MFMA
    u16x8 afr[4];
#pragma unroll
    for (int m = 0; m < 4; ++m)
      afr[m] = *(const u16x8*)(&lsE[16 * m + lh][slot * 64 + ks * 32 + lq * 8]);
#pragma unroll
    for (int t = 0; t < 4; ++t)
#pragma unroll
      for (int m = 0; m < 4; ++m) acc[m][t] = mfma16(afr[m], bst[t], acc[m][t]);
  };

  LOADS_A(0);
  LOADS_B(1);
  for (int s2 = 0; s2 < 16; s2 += 2) {
    WRITES(lda, 0);
    if (s2 + 2 < 16) LOADS_A(s2 + 2);
    BLOAD(s2, 0);                 // pre-barrier: drained alongside LDS writes
    __syncthreads();
    MCOMP1(0, 0);
    BLOAD(s2, 1);                 // L2-hot (~200cy), hidden under ks=0 MFMAs
    MCOMP1(0, 1);
    WRITES(ldb, 1);
    if (s2 + 3 < 16) LOADS_B(s2 + 3);
    BLOAD(s2 + 1, 0);
    __syncthreads();
    MCOMP1(1, 0);
    BLOAD(s2 + 1, 1);
    MCOMP1(1, 1);
  }
  __syncthreads();
#pragma unroll
  for (int t = 0; t < 4; ++t) {
    int col = wave * 64 + t * 16 + lh;
    float be = b_er[col];
#pragma unroll
    for (int m = 0; m < 4; ++m)
#pragma unroll
      for (int j = 0; j < 4; ++j)
        lsE[16 * m + 4 * lq + j][col] = f2bf(acc[m][t][j] + be);
  }
  __syncthreads();

  // ---------------- Phase A: sig1 (B 2-deep pipelined over ks) ----------------
  float prow[4][4];
#pragma unroll
  for (int m = 0; m < 4; ++m)
#pragma unroll
    for (int j = 0; j < 4; ++j) prow[m][j] = 0.f;
#pragma unroll
  for (int np = 0; np < 2; ++np) {
#pragma unroll
    for (int m = 0; m < 4; ++m)
#pragma unroll
      for (int t = 0; t < 4; ++t) acc[m][t] = zero4();
    u16x8 bcur[4];
#pragma unroll
    for (int t = 0; t < 4; ++t)
      bcur[t] = *(const u16x8*)(Wl1 + (size_t)(wave * 128 + np * 64 + t * 16 + lh) * MSGD + lq * 8);
#pragma unroll
    for (int ks = 0; ks < 8; ++ks) {
      u16x8 bnxt[4];
      if (ks < 7) {
#pragma unroll
        for (int t = 0; t < 4; ++t)
          bnxt[t] = *(const u16x8*)(Wl1 + (size_t)(wave * 128 + np * 64 + t * 16 + lh) * MSGD +
                                    (ks + 1) * 32 + lq * 8);
      }
      u16x8 afr[4];
#pragma unroll
      for (int m = 0; m < 4; ++m) afr[m] = *(const u16x8*)(&lsE[16 * m + lh][ks * 32 + lq * 8]);
#pragma unroll
      for (int t = 0; t < 4; ++t)
#pragma unroll
        for (int m = 0; m < 4; ++m) acc[m][t] = mfma16(afr[m], bcur[t], acc[m][t]);
      if (ks < 7) {
#pragma unroll
        for (int t = 0; t < 4; ++t) bcur[t] = bnxt[t];
      }
    }
#pragma unroll
    for (int t = 0; t < 4; ++t) {
      int col = wave * 128 + np * 64 + t * 16 + lh;
      float bl = b_l1[col], wl = W_l2[col];
#pragma unroll
      for (int m = 0; m < 4; ++m)
#pragma unroll
        for (int j = 0; j < 4; ++j) prow[m][j] += fmaxf(acc[m][t][j] + bl, 0.f) * wl;
    }
  }
#pragma unroll
  for (int off = 1; off < 16; off <<= 1)
#pragma unroll
    for (int m = 0; m < 4; ++m)
#pragma unroll
      for (int j = 0; j < 4; ++j) prow[m][j] += __shfl_xor(prow[m][j], off, 64);
  if (lh == 0) {
#pragma unroll
    for (int m = 0; m < 4; ++m)
#pragma unroll
      for (int j = 0; j < 4; ++j) lsPA[wave][16 * m + 4 * lq + j] = prow[m][j];
  }
  __syncthreads();
  if (tid < 64) {
    float pa1 = lsPA[0][tid] + lsPA[1][tid] + lsPA[2][tid] + lsPA[3][tid] + b_l2[0];
    lsSig[tid] = sigm(pa1);
  }
  // stage msg_h rows [w0, w0+64)
#pragma unroll
  for (int i = 0; i < 8; ++i) {
    int idx = tid + i * 256;
    int row = idx >> 5;
    int c8 = (idx & 31) << 3;
    *(u16x8*)(&lsM[row][c8]) =
        *(const u16x8*)(msgh + (size_t)(bb * NND + w0 + row) * MSGD + c8);
  }
  __syncthreads();

  // ---------------- Phase B: M0 (B 2-deep pipelined) ----------------
#pragma unroll
  for (int m = 0; m < 4; ++m)
#pragma unroll
    for (int t = 0; t < 4; ++t) acc[m][t] = zero4();
  {
    u16x8 bcur[4];
#pragma unroll
    for (int t = 0; t < 4; ++t)
      bcur[t] = *(const u16x8*)(Wm + (size_t)(wave * 64 + t * 16 + lh) * 512 + 256 + lq * 8);
#pragma unroll
    for (int ks = 0; ks < 8; ++ks) {
      u16x8 bnxt[4];
      if (ks < 7) {
#pragma unroll
        for (int t = 0; t < 4; ++t)
          bnxt[t] = *(const u16x8*)(Wm + (size_t)(wave * 64 + t * 16 + lh) * 512 + 256 +
                                    (ks + 1) * 32 + lq * 8);
      }
      u16x8 afr[4];
#pragma unroll
      for (int m = 0; m < 4; ++m) afr[m] = *(const u16x8*)(&lsE[16 * m + lh][ks * 32 + lq * 8]);
#pragma unroll
      for (int t = 0; t < 4; ++t)
#pragma unroll
        for (int m = 0; m < 4; ++m) acc[m][t] = mfma16(afr[m], bcur[t], acc[m][t]);
      if (ks < 7) {
#pragma unroll
        for (int t = 0; t < 4; ++t) bcur[t] = bnxt[t];
      }
    }
  }
#pragma unroll
  for (int t = 0; t < 4; ++t) {
    int col = wave * 64 + t * 16 + lh;
    float bm = b_m[col];
#pragma unroll
    for (int m = 0; m < 4; ++m)
#pragma unroll
      for (int j = 0; j < 4; ++j) {
        int row = 16 * m + 4 * lq + j;
        float mh = bf2f(lsM[row][col]);
        lsM[row][col] = f2bf(fmaxf(acc[m][t][j] + bm + mh, 0.f));
      }
  }
  __syncthreads();
#pragma unroll
  for (int i = 0; i < 8; ++i) {
    int idx = tid + i * 256;
    int row = idx >> 5;
    int c8 = (idx & 31) << 3;
    u16x8 m0v = *(const u16x8*)(&lsM[row][c8]);
    if (M0g) *(u16x8*)(M0g + (size_t)(base + row) * MSGD + c8) = m0v;
    float s = lsSig[row];
    u16x8 sc;
#pragma unroll
    for (int j = 0; j < 8; ++j) sc[j] = f2bf(bf2f(m0v[j]) * s);
    *(u16x8*)(&lsM[row][c8]) = sc;
  }
  __syncthreads();

  // ---------------- Phase C: pred_adj2 (B 2-deep pipelined; scatter transposed) ----------------
#pragma unroll
  for (int m = 0; m < 4; ++m)
#pragma unroll
    for (int j = 0; j < 4; ++j) prow[m][j] = 0.f;
#pragma unroll
  for (int np = 0; np < 2; ++np) {
#pragma unroll
    for (int m = 0; m < 4; ++m)
#pragma unroll
      for (int t = 0; t < 4; ++t) acc[m][t] = zero4();
    u16x8 bcur[4];
#pragma unroll
    for (int t = 0; t < 4; ++t)
      bcur[t] = *(const u16x8*)(Wl1 + (size_t)(wave * 128 + np * 64 + t * 16 + lh) * MSGD + lq * 8);
#pragma unroll
    for (int ks = 0; ks < 8; ++ks) {
      u16x8 bnxt[4];
      if (ks < 7) {
#pragma unroll
        for (int t = 0; t < 4; ++t)
          bnxt[t] = *(const u16x8*)(Wl1 + (size_t)(wave * 128 + np * 64 + t * 16 + lh) * MSGD +
                                    (ks + 1) * 32 + lq * 8);
      }
      u16x8 afr[4];
#pragma unroll
      for (int m = 0; m < 4; ++m) afr[m] = *(const u16x8*)(&lsM[16 * m + lh][ks * 32 + lq * 8]);
#pragma unroll
      for (int t = 0; t < 4; ++t)
#pragma unroll
        for (int m = 0; m < 4; ++m) acc[m][t] = mfma16(afr[m], bcur[t], acc[m][t]);
      if (ks < 7) {
#pragma unroll
        for (int t = 0; t < 4; ++t) bcur[t] = bnxt[t];
      }
    }
#pragma unroll
    for (int t = 0; t < 4; ++t) {
      int col = wave * 128 + np * 64 + t * 16 + lh;
      float bl = b_l1[col], wl = W_l2[col];
#pragma unroll
      for (int m = 0; m < 4; ++m)
#pragma unroll
        for (int j = 0; j < 4; ++j) prow[m][j] += fmaxf(acc[m][t][j] + bl, 0.f) * wl;
    }
  }
#pragma unroll
  for (int off = 1; off < 16; off <<= 1)
#pragma unroll
    for (int m = 0; m < 4; ++m)
#pragma unroll
      for (int j = 0; j < 4; ++j) prow[m][j] += __shfl_xor(prow[m][j], off, 64);
  if (lh == 0) {
#pragma unroll
    for (int m = 0; m < 4; ++m)
#pragma unroll
      for (int j = 0; j < 4; ++j) lsPA[wave][16 * m + 4 * lq + j] = prow[m][j];
  }
  __syncthreads();
  if (tid < 64) {
    float q = lsPA[0][tid] + lsPA[1][tid] + lsPA[2][tid] + lsPA[3][tid] + b_l2[0];
    size_t o = ((size_t)bb * NND + (w0 + tid)) * NND + vv;
    pa_out[o] = q;
  }
}

// ---------------------------------------------------------------- m_sum from stored M0 (coalesced)
__global__ __launch_bounds__(256) void k_msum_lite(const u16* __restrict__ M0g,
                                                   const float* __restrict__ qv,
                                                   float* __restrict__ msum) {
  __shared__ float sig[128];
  __shared__ __align__(16) float part[8][256];
  const int bv = blockIdx.x, tid = threadIdx.x;
  if (tid < 128) sig[tid] = sigm(qv[(size_t)bv * NND + tid]);
  __syncthreads();
  const int cg = (tid & 31) * 8, rg = tid >> 5;
  float a[8];
#pragma unroll
  for (int j = 0; j < 8; ++j) a[j] = 0.f;
  for (int i = 0; i < 16; ++i) {
    int row = rg + i * 8;
    u16x8 v = *(const u16x8*)(M0g + ((size_t)bv * NND + row) * MSGD + cg);
    float s = sig[row];
#pragma unroll
    for (int j = 0; j < 8; ++j) a[j] += s * bf2f(v[j]);
  }
#pragma unroll
  for (int j = 0; j < 8; ++j) part[rg][cg + j] = a[j];
  __syncthreads();
  float r = 0.f;
#pragma unroll
  for (int g = 0; g < 8; ++g) r += part[g][tid];
  msum[(size_t)bv * MSGD + tid] = r;
}

// ---------------------------------------------------------------- tier2 m_sum: recompute via W_comb
__global__ __launch_bounds__(256, 2) void k_msum2(
    const float* __restrict__ edge, const u16* __restrict__ Wcomb,
    const float* __restrict__ bcomb, const u16* __restrict__ msgh,
    const float* __restrict__ qv, float* __restrict__ msum) {
  __shared__ __align__(16) u16 lsE[64][LDST];
  __shared__ __align__(16) u16 lsM[64][LDST];
  __shared__ float lsSig[64];
  const int tid = threadIdx.x, lane = tid & 63, wave = tid >> 6;
  const int lh = lane & 15, lq = lane >> 4;
  const int bv = blockIdx.x;
  const int bb = bv >> 7;

  float csum[4] = {0.f, 0.f, 0.f, 0.f};

  for (int hh = 0; hh < 2; ++hh) {
    if (tid < 64) lsSig[tid] = sigm(qv[(size_t)bv * NND + hh * 64 + tid]);
#pragma unroll
    for (int i = 0; i < 8; ++i) {
      int idx = tid + i * 256;
      int row = idx >> 5;
      int c8 = (idx & 31) << 3;
      *(u16x8*)(&lsM[row][c8]) =
          *(const u16x8*)(msgh + (size_t)(bb * NND + hh * 64 + row) * MSGD + c8);
    }
    f32x4 acc[4][4];
#pragma unroll
    for (int m = 0; m < 4; ++m)
#pragma unroll
      for (int t = 0; t < 4; ++t) acc[m][t] = zero4();

    for (int kc = 0; kc < 4; ++kc) {
#pragma unroll
      for (int i = 0; i < 16; ++i) {
        int idx = tid + i * 256;
        int row = idx >> 6;
        int c4 = (idx & 63) << 2;
        float4 f = *(const float4*)(edge + (size_t)(bv * NND + hh * 64 + row) * FEATD + kc * 256 + c4);
        u16x4 o; o[0] = f2bf(f.x); o[1] = f2bf(f.y); o[2] = f2bf(f.z); o[3] = f2bf(f.w);
        *(u16x4*)(&lsE[row][c4]) = o;
      }
      __syncthreads();
#pragma unroll
      for (int ks = 0; ks < 8; ++ks) {
        u16x8 afr[4];
#pragma unroll
        for (int m = 0; m < 4; ++m) afr[m] = *(const u16x8*)(&lsE[16 * m + lh][ks * 32 + lq * 8]);
        const int kg = kc * 256 + ks * 32 + lq * 8;
#pragma unroll
        for (int t = 0; t < 4; ++t) {
          int col = wave * 64 + t * 16 + lh;
          u16x8 bfr = *(const u16x8*)(Wcomb + (size_t)col * FEATD + kg);
#pragma unroll
          for (int m = 0; m < 4; ++m) acc[m][t] = mfma16(afr[m], bfr, acc[m][t]);
        }
      }
      __syncthreads();
    }
#pragma unroll
    for (int t = 0; t < 4; ++t) {
      int col = wave * 64 + t * 16 + lh;
      float bc = bcomb[col];
#pragma unroll
      for (int m = 0; m < 4; ++m)
#pragma unroll
        for (int j = 0; j < 4; ++j) {
          int row = 16 * m + 4 * lq + j;
          float m0 = fmaxf(acc[m][t][j] + bc + bf2f(lsM[row][col]), 0.f);
          csum[t] += lsSig[row] * m0;
        }
    }
    __syncthreads();
  }
#pragma unroll
  for (int off = 16; off < 64; off <<= 1)
#pragma unroll
    for (int t = 0; t < 4; ++t) csum[t] += __shfl_xor(csum[t], off, 64);
  if (lq == 0) {
#pragma unroll
    for (int t = 0; t < 4; ++t)
      msum[(size_t)bv * MSGD + wave * 64 + t * 16 + lh] = csum[t];
  }
}

// ---------------------------------------------------------------- GRU + labels (8 rows / block, grid 128 — proven)
__global__ __launch_bounds__(256) void k_gru(const float* __restrict__ msum,
                                             const float* __restrict__ h32,
                                             const float* __restrict__ Wih, const float* __restrict__ bih,
                                             const float* __restrict__ Whh, const float* __restrict__ bhh,
                                             const float* __restrict__ Wr, const float* __restrict__ br,
                                             float* __restrict__ outlab) {
  __shared__ __align__(16) float sM[8][256];
  __shared__ __align__(16) float sH[8][256];
  __shared__ __align__(16) float sHn[8][256];
  const int tid = threadIdx.x;
  const int r0 = blockIdx.x * 8;
#pragma unroll
  for (int i = 0; i < 2; ++i) {
    int idx = tid + i * 256;
    int row = idx >> 6;
    int c = (idx & 63) << 2;
    *(float4*)(&sM[row][c]) = *(const float4*)(msum + (size_t)(r0 + row) * 256 + c);
    *(float4*)(&sH[row][c]) = *(const float4*)(h32 + (size_t)(r0 + row) * 256 + c);
  }
  __syncthreads();
  float gi[3][8], gh[3][8];
#pragma unroll
  for (int c = 0; c < 3; ++c) {
    float bi_ = bih[tid + 256 * c], bh_ = bhh[tid + 256 * c];
#pragma unroll
    for (int rr = 0; rr < 8; ++rr) { gi[c][rr] = bi_; gh[c][rr] = bh_; }
  }
  for (int k = 0; k < 256; k += 4) {
    float4 wi[3], wh[3];
#pragma unroll
    for (int c = 0; c < 3; ++c) {
      wi[c] = *(const float4*)(Wih + (size_t)(tid + 256 * c) * 256 + k);
      wh[c] = *(const float4*)(Whh + (size_t)(tid + 256 * c) * 256 + k);
    }
#pragma unroll
    for (int rr = 0; rr < 8; ++rr) {
      float4 ms = *(const float4*)(&sM[rr][k]);
      float4 hh = *(const float4*)(&sH[rr][k]);
#pragma unroll
      for (int c = 0; c < 3; ++c) {
        gi[c][rr] += wi[c].x * ms.x + wi[c].y * ms.y + wi[c].z * ms.z + wi[c].w * ms.w;
        gh[c][rr] += wh[c].x * hh.x + wh[c].y * hh.y + wh[c].z * hh.z + wh[c].w * hh.w;
      }
    }
  }
#pragma unroll
  for (int rr = 0; rr < 8; ++rr) {
    float r = sigm(gi[0][rr] + gh[0][rr]);
    float z = sigm(gi[1][rr] + gh[1][rr]);
    float n = tanhf(gi[2][rr] + r * gh[2][rr]);
    sHn[rr][tid] = (1.f - z) * n + z * sH[rr][tid];
  }
  __syncthreads();
  float lab[3][8];
  int cs[3]; bool has[3];
#pragma unroll
  for (int c = 0; c < 3; ++c) {
    cs[c] = tid + 256 * c;
    has[c] = cs[c] < CLSD;
    float b0 = has[c] ? br[cs[c]] : 0.f;
#pragma unroll
    for (int rr = 0; rr < 8; ++rr) lab[c][rr] = b0;
  }
  for (int k = 0; k < 256; k += 4) {
    float4 wr[3];
#pragma unroll
    for (int c = 0; c < 3; ++c) {
      if (has[c]) wr[c] = *(const float4*)(Wr + (size_t)cs[c] * 256 + k);
      else { wr[c].x = 0.f; wr[c].y = 0.f; wr[c].z = 0.f; wr[c].w = 0.f; }
    }
#pragma unroll
    for (int rr = 0; rr < 8; ++rr) {
      float4 hv = *(const float4*)(&sHn[rr][k]);
#pragma unroll
      for (int c = 0; c < 3; ++c)
        lab[c][rr] += wr[c].x * hv.x + wr[c].y * hv.y + wr[c].z * hv.z + wr[c].w * hv.w;
    }
  }
#pragma unroll
  for (int c = 0; c < 3; ++c) {
    if (has[c]) {
#pragma unroll
      for (int rr = 0; rr < 8; ++rr)
        outlab[(size_t)(r0 + rr) * CLSD + cs[c]] = lab[c][rr];
    }
  }
}

// ---------------------------------------------------------------- launch
extern "C" void kernel_launch(void* const* d_in, const int* in_sizes, int n_in,
                              void* d_out, int out_size, void* d_ws, size_t ws_size,
                              hipStream_t stream) {
  const float* edge = (const float*)d_in[0];
  const float* node = (const float*)d_in[1];
  const float* W_er = (const float*)d_in[6];
  const float* b_er = (const float*)d_in[7];
  const float* W_nr = (const float*)d_in[8];
  const float* b_nr = (const float*)d_in[9];
  const float* W_l1 = (const float*)d_in[10];
  const float* b_l1 = (const float*)d_in[11];
  const float* W_l2 = (const float*)d_in[12];
  const float* b_l2 = (const float*)d_in[13];
  const float* W_m  = (const float*)d_in[14];
  const float* b_m  = (const float*)d_in[15];
  const float* W_ih = (const float*)d_in[16];
  const float* b_ih = (const float*)d_in[17];
  const float* W_hh = (const float*)d_in[18];
  const float* b_hh = (const float*)d_in[19];
  const float* W_r  = (const float*)d_in[20];
  const float* b_r  = (const float*)d_in[21];

  char* ws = (char*)d_ws;
  size_t off = 0;
  auto alloc = [&](size_t bytes) -> void* {
    void* p = ws + off;
    off += (bytes + 511) & ~(size_t)511;
    return p;
  };
  u16* WerB     = (u16*)alloc((size_t)262144 * 2);
  u16* WmB      = (u16*)alloc((size_t)131072 * 2);
  u16* Wl1B     = (u16*)alloc((size_t)131072 * 2);
  u16* WcombB   = (u16*)alloc((size_t)262144 * 2);
  float* bcombF = (float*)alloc((size_t)256 * 4);
  u16* msghB    = (u16*)alloc((size_t)262144 * 2);
  float* h32    = (float*)alloc((size_t)262144 * 4);
  float* msum   = (float*)alloc((size_t)262144 * 4);
  u16* M0g      = (u16*)alloc((size_t)33554432 * 2);   // 64 MiB
  size_t off_m0 = off;
  const bool fast = (ws_size >= off_m0);
  u16* M0arg = fast ? M0g : (u16*)nullptr;

  float* out_pa  = (float*)d_out;
  float* out_lab = out_pa + 131072;

  k_cvt  <<<256,  256, 0, stream>>>(W_er, WerB, 262144);
  k_cvt  <<<128,  256, 0, stream>>>(W_m,  WmB,  131072);
  k_cvt  <<<128,  256, 0, stream>>>(W_l1, Wl1B, 131072);
  s1_hmsg<<<1024, 256, 0, stream>>>(node, W_nr, b_nr, W_m, h32, msghB);
  if (!fast)
    k_comb<<<1024, 256, 0, stream>>>(W_m, W_er, b_er, b_m, WcombB, bcombF);

  k_main_full<<<2048, 256, 0, stream>>>(edge, WerB, WmB, Wl1B, b_er, b_m, b_l1, W_l2, b_l2,
                                        msghB, M0arg, out_pa);
  if (fast)
    k_msum_lite<<<1024, 256, 0, stream>>>(M0g, out_pa, msum);
  else
    k_msum2<<<1024, 256, 0, stream>>>(edge, WcombB, bcombF, msghB, out_pa, msum);
  k_gru<<<128, 256, 0, stream>>>(msum, h32, W_ih, b_ih, W_hh, b_hh, W_r, b_r, out_lab);
}

// Round 15
// 643.074 us; speedup vs baseline: 1.1447x; 1.1447x over previous
//
#include <hip/hip_runtime.h>
#include <cstdint>
#include <cstddef>

#define NND   128
#define FEATD 1024
#define MSGD  256
#define LHD   512
#define CLSD  600
#define LDST  264   // padded LDS row stride (528B, 16B-aligned)

typedef __bf16 bf16_t;
typedef bf16_t bf16x8 __attribute__((ext_vector_type(8)));
typedef float  f32x4  __attribute__((ext_vector_type(4)));
typedef unsigned short u16;
typedef u16 u16x8 __attribute__((ext_vector_type(8)));
typedef u16 u16x4 __attribute__((ext_vector_type(4)));

static __device__ __forceinline__ float bf2f(u16 u) {
  union { unsigned u; float f; } x; x.u = ((unsigned)u) << 16; return x.f;
}
static __device__ __forceinline__ u16 f2bf(float f) {
  union { float f; unsigned u; } x; x.f = f;
  return (u16)((x.u + 0x7fffu + ((x.u >> 16) & 1u)) >> 16);  // RNE
}
static __device__ __forceinline__ f32x4 mfma16(u16x8 a, u16x8 b, f32x4 c) {
  return __builtin_amdgcn_mfma_f32_16x16x32_bf16(
      __builtin_bit_cast(bf16x8, a), __builtin_bit_cast(bf16x8, b), c, 0, 0, 0);
}
static __device__ __forceinline__ f32x4 zero4() {
  f32x4 v; v[0] = 0.f; v[1] = 0.f; v[2] = 0.f; v[3] = 0.f; return v;
}
static __device__ __forceinline__ float sigm(float x) { return 1.0f / (1.0f + expf(-x)); }

// ---------------------------------------------------------------- weight cvt f32->bf16
__global__ void k_cvt(const float* __restrict__ src, u16* __restrict__ dst, int n) {
  int i = (blockIdx.x * 256 + threadIdx.x) * 4;
  if (i + 3 < n) {
    float4 f = *(const float4*)(src + i);
    u16x4 o; o[0] = f2bf(f.x); o[1] = f2bf(f.y); o[2] = f2bf(f.z); o[3] = f2bf(f.w);
    *(u16x4*)(dst + i) = o;
  }
}

// ---------------------------------------------------------------- W_comb (tier2 fallback only)
__global__ __launch_bounds__(256) void k_comb(const float* __restrict__ Wm,
                                              const float* __restrict__ Wer,
                                              const float* __restrict__ b_er,
                                              const float* __restrict__ b_m,
                                              u16* __restrict__ WcombB,
                                              float* __restrict__ bcomb) {
  const int m = blockIdx.x >> 2, ch = blockIdx.x & 3;
  const int d = ch * 256 + threadIdx.x;
  float s = 0.f;
  for (int k = 0; k < 256; ++k)
    s += Wm[(size_t)m * 512 + 256 + k] * Wer[(size_t)k * FEATD + d];
  WcombB[(size_t)m * FEATD + d] = f2bf(s);
  if (ch == 0 && threadIdx.x == 0) {
    float bb2 = b_m[m];
    for (int k = 0; k < 256; ++k) bb2 += Wm[(size_t)m * 512 + 256 + k] * b_er[k];
    bcomb[m] = bb2;
  }
}

// ---------------------------------------------------------------- S1 v2: wave-cooperative dots (coalesced Wnr reads)
// h[r][col] = nrow . Wnr[col] + bnr[col]; msg_h[r][col] = hrow . Wm[col][:256]
__global__ __launch_bounds__(256) void s1_hmsg2(const float* __restrict__ node,
                                                const float* __restrict__ Wnr,
                                                const float* __restrict__ bnr,
                                                const float* __restrict__ Wm,
                                                float* __restrict__ h32,
                                                u16* __restrict__ msghB) {
  __shared__ __align__(16) float nrow[FEATD];
  __shared__ __align__(16) float hrow[MSGD];
  const int r = blockIdx.x;            // 0..1023 = b*128 + n
  const int tid = threadIdx.x, lane = tid & 63, wave = tid >> 6;
  *(float4*)(&nrow[tid * 4]) = *(const float4*)(node + (size_t)r * FEATD + tid * 4);
  __syncthreads();
  // h: wave w computes cols [w*64, w*64+64); lane-contiguous float4 reads of Wnr row
  for (int i = 0; i < 64; ++i) {
    const int col = wave * 64 + i;
    const float* wp = Wnr + (size_t)col * FEATD + lane * 16;
    const float* np = &nrow[lane * 16];
    float s = 0.f;
#pragma unroll
    for (int j = 0; j < 4; ++j) {
      float4 w4 = *(const float4*)(wp + j * 4);
      float4 n4 = *(const float4*)(np + j * 4);
      s += w4.x * n4.x + w4.y * n4.y + w4.z * n4.z + w4.w * n4.w;
    }
#pragma unroll
    for (int off = 1; off < 64; off <<= 1) s += __shfl_xor(s, off, 64);
    if (lane == 0) hrow[col] = s + bnr[col];
  }
  __syncthreads();
  h32[(size_t)r * MSGD + tid] = hrow[tid];
  // msg_h: dot over 256 (Wm left half), 4 floats/lane
  for (int i = 0; i < 64; ++i) {
    const int col = wave * 64 + i;
    float4 w4 = *(const float4*)(Wm + (size_t)col * 512 + lane * 4);
    float4 h4 = *(const float4*)(&hrow[lane * 4]);
    float s = w4.x * h4.x + w4.y * h4.y + w4.z * h4.z + w4.w * h4.w;
#pragma unroll
    for (int off = 1; off < 64; off <<= 1) s += __shfl_xor(s, off, 64);
    if (lane == 0) msghB[(size_t)r * MSGD + col] = f2bf(s);
  }
}

// ---------------------------------------------------------------- main monolith — R11 exact ((256,2): 443us best known;
// accepts ~70-reg spill (295MB HBM writes) as the cheaper regime vs 1-wave no-spill (455us, R13))
__global__ __launch_bounds__(256, 2) void k_main_full(
    const float* __restrict__ edge, const u16* __restrict__ Wer, const u16* __restrict__ Wm,
    const u16* __restrict__ Wl1, const float* __restrict__ b_er, const float* __restrict__ b_m,
    const float* __restrict__ b_l1, const float* __restrict__ W_l2, const float* __restrict__ b_l2,
    const u16* __restrict__ msgh, u16* __restrict__ M0g, float* __restrict__ pa_out) {
  __shared__ __align__(16) u16 lsE[64][LDST];
  __shared__ __align__(16) u16 lsM[64][LDST];
  __shared__ float lsPA[4][64];
  __shared__ float lsSig[64];

  const int tid = threadIdx.x, lane = tid & 63, wave = tid >> 6;
  const int lh = lane & 15, lq = lane >> 4;
  const int base = blockIdx.x * 64;
  const int bb = base >> 14, vv = (base >> 7) & 127, w0 = base & 127;

  f32x4 acc[4][4];
#pragma unroll
  for (int m = 0; m < 4; ++m)
#pragma unroll
    for (int t = 0; t < 4; ++t) acc[m][t] = zero4();

  // ---------------- Phase 0: 16 K-steps of BK=64; B issued pre-barrier, compute is LDS-only ----------------
  const int srow = tid >> 2;
  const int scq  = (tid & 3) * 16;
  const float* esrc = edge + (size_t)(base + srow) * FEATD + scq;
  float4 lda[4], ldb[4];
  u16x8 bst[2][4];

  auto LOADS_A = [&](int s) {
#pragma unroll
    for (int i = 0; i < 4; ++i) lda[i] = *(const float4*)(esrc + s * 64 + i * 4);
  };
  auto LOADS_B = [&](int s) {
#pragma unroll
    for (int i = 0; i < 4; ++i) ldb[i] = *(const float4*)(esrc + s * 64 + i * 4);
  };
  auto WRITES = [&](const float4* ld, int slot) {
    u16* wp = &lsE[srow][slot * 64 + scq];
    u16x8 o0, o1;
    o0[0] = f2bf(ld[0].x); o0[1] = f2bf(ld[0].y); o0[2] = f2bf(ld[0].z); o0[3] = f2bf(ld[0].w);
    o0[4] = f2bf(ld[1].x); o0[5] = f2bf(ld[1].y); o0[6] = f2bf(ld[1].z); o0[7] = f2bf(ld[1].w);
    o1[0] = f2bf(ld[2].x); o1[1] = f2bf(ld[2].y); o1[2] = f2bf(ld[2].z); o1[3] = f2bf(ld[2].w);
    o1[4] = f2bf(ld[3].x); o1[5] = f2bf(ld[3].y); o1[6] = f2bf(ld[3].z); o1[7] = f2bf(ld[3].w);
    *(u16x8*)wp = o0;
    *(u16x8*)(wp + 8) = o1;
  };
  auto BLOAD = [&](int sk) {
#pragma unroll
    for (int ks = 0; ks < 2; ++ks)
#pragma unroll
      for (int t = 0; t < 4; ++t) {
        int col = wave * 64 + t * 16 + lh;
        bst[ks][t] = *(const u16x8*)(Wer + (size_t)col * FEATD + sk * 64 + ks * 32 + lq * 8);
      }
  };
  auto MCOMP = [&](int slot) {
#pragma unroll
    for (int ks = 0; ks < 2; ++ks) {
      u16x8 afr[4];
#pragma unroll
      for (int m = 0; m < 4; ++m)
        afr[m] = *(const u16x8*)(&lsE[16 * m + lh][slot * 64 + ks * 32 + lq * 8]);
#pragma unroll
      for (int t = 0; t < 4; ++t)
#pragma unroll
        for (int m = 0; m < 4; ++m) acc[m][t] = mfma16(afr[m], bst[ks][t], acc[m][t]);
    }
  };

  LOADS_A(0);
  LOADS_B(1);
  for (int s2 = 0; s2 < 16; s2 += 2) {
    WRITES(lda, 0);
    if (s2 + 2 < 16) LOADS_A(s2 + 2);
    BLOAD(s2);
    __syncthreads();
    MCOMP(0);
    WRITES(ldb, 1);
    if (s2 + 3 < 16) LOADS_B(s2 + 3);
    BLOAD(s2 + 1);
    __syncthreads();
    MCOMP(1);
  }
  __syncthreads();
#pragma unroll
  for (int t = 0; t < 4; ++t) {
    int col = wave * 64 + t * 16 + lh;
    float be = b_er[col];
#pragma unroll
    for (int m = 0; m < 4; ++m)
#pragma unroll
      for (int j = 0; j < 4; ++j)
        lsE[16 * m + 4 * lq + j][col] = f2bf(acc[m][t][j] + be);
  }
  __syncthreads();

  // ---------------- Phase A: sig1 (B 2-deep pipelined over ks) ----------------
  float prow[4][4];
#pragma unroll
  for (int m = 0; m < 4; ++m)
#pragma unroll
    for (int j = 0; j < 4; ++j) prow[m][j] = 0.f;
#pragma unroll
  for (int np = 0; np < 2; ++np) {
#pragma unroll
    for (int m = 0; m < 4; ++m)
#pragma unroll
      for (int t = 0; t < 4; ++t) acc[m][t] = zero4();
    u16x8 bcur[4];
#pragma unroll
    for (int t = 0; t < 4; ++t)
      bcur[t] = *(const u16x8*)(Wl1 + (size_t)(wave * 128 + np * 64 + t * 16 + lh) * MSGD + lq * 8);
#pragma unroll
    for (int ks = 0; ks < 8; ++ks) {
      u16x8 bnxt[4];
      if (ks < 7) {
#pragma unroll
        for (int t = 0; t < 4; ++t)
          bnxt[t] = *(const u16x8*)(Wl1 + (size_t)(wave * 128 + np * 64 + t * 16 + lh) * MSGD +
                                    (ks + 1) * 32 + lq * 8);
      }
      u16x8 afr[4];
#pragma unroll
      for (int m = 0; m < 4; ++m) afr[m] = *(const u16x8*)(&lsE[16 * m + lh][ks * 32 + lq * 8]);
#pragma unroll
      for (int t = 0; t < 4; ++t)
#pragma unroll
        for (int m = 0; m < 4; ++m) acc[m][t] = mfma16(afr[m], bcur[t], acc[m][t]);
      if (ks < 7) {
#pragma unroll
        for (int t = 0; t < 4; ++t) bcur[t] = bnxt[t];
      }
    }
#pragma unroll
    for (int t = 0; t < 4; ++t) {
      int col = wave * 128 + np * 64 + t * 16 + lh;
      float bl = b_l1[col], wl = W_l2[col];
#pragma unroll
      for (int m = 0; m < 4; ++m)
#pragma unroll
        for (int j = 0; j < 4; ++j) prow[m][j] += fmaxf(acc[m][t][j] + bl, 0.f) * wl;
    }
  }
#pragma unroll
  for (int off = 1; off < 16; off <<= 1)
#pragma unroll
    for (int m = 0; m < 4; ++m)
#pragma unroll
      for (int j = 0; j < 4; ++j) prow[m][j] += __shfl_xor(prow[m][j], off, 64);
  if (lh == 0) {
#pragma unroll
    for (int m = 0; m < 4; ++m)
#pragma unroll
      for (int j = 0; j < 4; ++j) lsPA[wave][16 * m + 4 * lq + j] = prow[m][j];
  }
  __syncthreads();
  if (tid < 64) {
    float pa1 = lsPA[0][tid] + lsPA[1][tid] + lsPA[2][tid] + lsPA[3][tid] + b_l2[0];
    lsSig[tid] = sigm(pa1);
  }
  // stage msg_h rows [w0, w0+64)
#pragma unroll
  for (int i = 0; i < 8; ++i) {
    int idx = tid + i * 256;
    int row = idx >> 5;
    int c8 = (idx & 31) << 3;
    *(u16x8*)(&lsM[row][c8]) =
        *(const u16x8*)(msgh + (size_t)(bb * NND + w0 + row) * MSGD + c8);
  }
  __syncthreads();

  // ---------------- Phase B: M0 (B 2-deep pipelined) ----------------
#pragma unroll
  for (int m = 0; m < 4; ++m)
#pragma unroll
    for (int t = 0; t < 4; ++t) acc[m][t] = zero4();
  {
    u16x8 bcur[4];
#pragma unroll
    for (int t = 0; t < 4; ++t)
      bcur[t] = *(const u16x8*)(Wm + (size_t)(wave * 64 + t * 16 + lh) * 512 + 256 + lq * 8);
#pragma unroll
    for (int ks = 0; ks < 8; ++ks) {
      u16x8 bnxt[4];
      if (ks < 7) {
#pragma unroll
        for (int t = 0; t < 4; ++t)
          bnxt[t] = *(const u16x8*)(Wm + (size_t)(wave * 64 + t * 16 + lh) * 512 + 256 +
                                    (ks + 1) * 32 + lq * 8);
      }
      u16x8 afr[4];
#pragma unroll
      for (int m = 0; m < 4; ++m) afr[m] = *(const u16x8*)(&lsE[16 * m + lh][ks * 32 + lq * 8]);
#pragma unroll
      for (int t = 0; t < 4; ++t)
#pragma unroll
        for (int m = 0; m < 4; ++m) acc[m][t] = mfma16(afr[m], bcur[t], acc[m][t]);
      if (ks < 7) {
#pragma unroll
        for (int t = 0; t < 4; ++t) bcur[t] = bnxt[t];
      }
    }
  }
#pragma unroll
  for (int t = 0; t < 4; ++t) {
    int col = wave * 64 + t * 16 + lh;
    float bm = b_m[col];
#pragma unroll
    for (int m = 0; m < 4; ++m)
#pragma unroll
      for (int j = 0; j < 4; ++j) {
        int row = 16 * m + 4 * lq + j;
        float mh = bf2f(lsM[row][col]);
        lsM[row][col] = f2bf(fmaxf(acc[m][t][j] + bm + mh, 0.f));
      }
  }
  __syncthreads();
#pragma unroll
  for (int i = 0; i < 8; ++i) {
    int idx = tid + i * 256;
    int row = idx >> 5;
    int c8 = (idx & 31) << 3;
    u16x8 m0v = *(const u16x8*)(&lsM[row][c8]);
    if (M0g) *(u16x8*)(M0g + (size_t)(base + row) * MSGD + c8) = m0v;
    float s = lsSig[row];
    u16x8 sc;
#pragma unroll
    for (int j = 0; j < 8; ++j) sc[j] = f2bf(bf2f(m0v[j]) * s);
    *(u16x8*)(&lsM[row][c8]) = sc;
  }
  __syncthreads();

  // ---------------- Phase C: pred_adj2 (B 2-deep pipelined; scatter transposed) ----------------
#pragma unroll
  for (int m = 0; m < 4; ++m)
#pragma unroll
    for (int j = 0; j < 4; ++j) prow[m][j] = 0.f;
#pragma unroll
  for (int np = 0; np < 2; ++np) {
#pragma unroll
    for (int m = 0; m < 4; ++m)
#pragma unroll
      for (int t = 0; t < 4; ++t) acc[m][t] = zero4();
    u16x8 bcur[4];
#pragma unroll
    for (int t = 0; t < 4; ++t)
      bcur[t] = *(const u16x8*)(Wl1 + (size_t)(wave * 128 + np * 64 + t * 16 + lh) * MSGD + lq * 8);
#pragma unroll
    for (int ks = 0; ks < 8; ++ks) {
      u16x8 bnxt[4];
      if (ks < 7) {
#pragma unroll
        for (int t = 0; t < 4; ++t)
          bnxt[t] = *(const u16x8*)(Wl1 + (size_t)(wave * 128 + np * 64 + t * 16 + lh) * MSGD +
                                    (ks + 1) * 32 + lq * 8);
      }
      u16x8 afr[4];
#pragma unroll
      for (int m = 0; m < 4; ++m) afr[m] = *(const u16x8*)(&lsM[16 * m + lh][ks * 32 + lq * 8]);
#pragma unroll
      for (int t = 0; t < 4; ++t)
#pragma unroll
        for (int m = 0; m < 4; ++m) acc[m][t] = mfma16(afr[m], bcur[t], acc[m][t]);
      if (ks < 7) {
#pragma unroll
        for (int t = 0; t < 4; ++t) bcur[t] = bnxt[t];
      }
    }
#pragma unroll
    for (int t = 0; t < 4; ++t) {
      int col = wave * 128 + np * 64 + t * 16 + lh;
      float bl = b_l1[col], wl = W_l2[col];
#pragma unroll
      for (int m = 0; m < 4; ++m)
#pragma unroll
        for (int j = 0; j < 4; ++j) prow[m][j] += fmaxf(acc[m][t][j] + bl, 0.f) * wl;
    }
  }
#pragma unroll
  for (int off = 1; off < 16; off <<= 1)
#pragma unroll
    for (int m = 0; m < 4; ++m)
#pragma unroll
      for (int j = 0; j < 4; ++j) prow[m][j] += __shfl_xor(prow[m][j], off, 64);
  if (lh == 0) {
#pragma unroll
    for (int m = 0; m < 4; ++m)
#pragma unroll
      for (int j = 0; j < 4; ++j) lsPA[wave][16 * m + 4 * lq + j] = prow[m][j];
  }
  __syncthreads();
  if (tid < 64) {
    float q = lsPA[0][tid] + lsPA[1][tid] + lsPA[2][tid] + lsPA[3][tid] + b_l2[0];
    size_t o = ((size_t)bb * NND + (w0 + tid)) * NND + vv;
    pa_out[o] = q;
  }
}

// ---------------------------------------------------------------- m_sum from stored M0 (coalesced)
__global__ __launch_bounds__(256) void k_msum_lite(const u16* __restrict__ M0g,
                                                   const float* __restrict__ qv,
                                                   float* __restrict__ msum) {
  __shared__ float sig[128];
  __shared__ __align__(16) float part[8][256];
  const int bv = blockIdx.x, tid = threadIdx.x;
  if (tid < 128) sig[tid] = sigm(qv[(size_t)bv * NND + tid]);
  __syncthreads();
  const int cg = (tid & 31) * 8, rg = tid >> 5;
  float a[8];
#pragma unroll
  for (int j = 0; j < 8; ++j) a[j] = 0.f;
  for (int i = 0; i < 16; ++i) {
    int row = rg + i * 8;
    u16x8 v = *(const u16x8*)(M0g + ((size_t)bv * NND + row) * MSGD + cg);
    float s = sig[row];
#pragma unroll
    for (int j = 0; j < 8; ++j) a[j] += s * bf2f(v[j]);
  }
#pragma unroll
  for (int j = 0; j < 8; ++j) part[rg][cg + j] = a[j];
  __syncthreads();
  float r = 0.f;
#pragma unroll
  for (int g = 0; g < 8; ++g) r += part[g][tid];
  msum[(size_t)bv * MSGD + tid] = r;
}

// ---------------------------------------------------------------- tier2 m_sum: recompute via W_comb
__global__ __launch_bounds__(256, 2) void k_msum2(
    const float* __restrict__ edge, const u16* __restrict__ Wcomb,
    const float* __restrict__ bcomb, const u16* __restrict__ msgh,
    const float* __restrict__ qv, float* __restrict__ msum) {
  __shared__ __align__(16) u16 lsE[64][LDST];
  __shared__ __align__(16) u16 lsM[64][LDST];
  __shared__ float lsSig[64];
  const int tid = threadIdx.x, lane = tid & 63, wave = tid >> 6;
  const int lh = lane & 15, lq = lane >> 4;
  const int bv = blockIdx.x;
  const int bb = bv >> 7;

  float csum[4] = {0.f, 0.f, 0.f, 0.f};

  for (int hh = 0; hh < 2; ++hh) {
    if (tid < 64) lsSig[tid] = sigm(qv[(size_t)bv * NND + hh * 64 + tid]);
#pragma unroll
    for (int i = 0; i < 8; ++i) {
      int idx = tid + i * 256;
      int row = idx >> 5;
      int c8 = (idx & 31) << 3;
      *(u16x8*)(&lsM[row][c8]) =
          *(const u16x8*)(msgh + (size_t)(bb * NND + hh * 64 + row) * MSGD + c8);
    }
    f32x4 acc[4][4];
#pragma unroll
    for (int m = 0; m < 4; ++m)
#pragma unroll
      for (int t = 0; t < 4; ++t) acc[m][t] = zero4();

    for (int kc = 0; kc < 4; ++kc) {
#pragma unroll
      for (int i = 0; i < 16; ++i) {
        int idx = tid + i * 256;
        int row = idx >> 6;
        int c4 = (idx & 63) << 2;
        float4 f = *(const float4*)(edge + (size_t)(bv * NND + hh * 64 + row) * FEATD + kc * 256 + c4);
        u16x4 o; o[0] = f2bf(f.x); o[1] = f2bf(f.y); o[2] = f2bf(f.z); o[3] = f2bf(f.w);
        *(u16x4*)(&lsE[row][c4]) = o;
      }
      __syncthreads();
#pragma unroll
      for (int ks = 0; ks < 8; ++ks) {
        u16x8 afr[4];
#pragma unroll
        for (int m = 0; m < 4; ++m) afr[m] = *(const u16x8*)(&lsE[16 * m + lh][ks * 32 + lq * 8]);
        const int kg = kc * 256 + ks * 32 + lq * 8;
#pragma unroll
        for (int t = 0; t < 4; ++t) {
          int col = wave * 64 + t * 16 + lh;
          u16x8 bfr = *(const u16x8*)(Wcomb + (size_t)col * FEATD + kg);
#pragma unroll
          for (int m = 0; m < 4; ++m) acc[m][t] = mfma16(afr[m], bfr, acc[m][t]);
        }
      }
      __syncthreads();
    }
#pragma unroll
    for (int t = 0; t < 4; ++t) {
      int col = wave * 64 + t * 16 + lh;
      float bc = bcomb[col];
#pragma unroll
      for (int m = 0; m < 4; ++m)
#pragma unroll
        for (int j = 0; j < 4; ++j) {
          int row = 16 * m + 4 * lq + j;
          float m0 = fmaxf(acc[m][t][j] + bc + bf2f(lsM[row][col]), 0.f);
          csum[t] += lsSig[row] * m0;
        }
    }
    __syncthreads();
  }
#pragma unroll
  for (int off = 16; off < 64; off <<= 1)
#pragma unroll
    for (int t = 0; t < 4; ++t) csum[t] += __shfl_xor(csum[t], off, 64);
  if (lq == 0) {
#pragma unroll
    for (int t = 0; t < 4; ++t)
      msum[(size_t)bv * MSGD + wave * 64 + t * 16 + lh] = csum[t];
  }
}

// ---------------------------------------------------------------- GRU + labels (8 rows / block, grid 128 — proven)
__global__ __launch_bounds__(256) void k_gru(const float* __restrict__ msum,
                                             const float* __restrict__ h32,
                                             const float* __restrict__ Wih, const float* __restrict__ bih,
                                             const float* __restrict__ Whh, const float* __restrict__ bhh,
                                             const float* __restrict__ Wr, const float* __restrict__ br,
                                             float* __restrict__ outlab) {
  __shared__ __align__(16) float sM[8][256];
  __shared__ __align__(16) float sH[8][256];
  __shared__ __align__(16) float sHn[8][256];
  const int tid = threadIdx.x;
  const int r0 = blockIdx.x * 8;
#pragma unroll
  for (int i = 0; i < 2; ++i) {
    int idx = tid + i * 256;
    int row = idx >> 6;
    int c = (idx & 63) << 2;
    *(float4*)(&sM[row][c]) = *(const float4*)(msum + (size_t)(r0 + row) * 256 + c);
    *(float4*)(&sH[row][c]) = *(const float4*)(h32 + (size_t)(r0 + row) * 256 + c);
  }
  __syncthreads();
  float gi[3][8], gh[3][8];
#pragma unroll
  for (int c = 0; c < 3; ++c) {
    float bi_ = bih[tid + 256 * c], bh_ = bhh[tid + 256 * c];
#pragma unroll
    for (int rr = 0; rr < 8; ++rr) { gi[c][rr] = bi_; gh[c][rr] = bh_; }
  }
  for (int k = 0; k < 256; k += 4) {
    float4 wi[3], wh[3];
#pragma unroll
    for (int c = 0; c < 3; ++c) {
      wi[c] = *(const float4*)(Wih + (size_t)(tid + 256 * c) * 256 + k);
      wh[c] = *(const float4*)(Whh + (size_t)(tid + 256 * c) * 256 + k);
    }
#pragma unroll
    for (int rr = 0; rr < 8; ++rr) {
      float4 ms = *(const float4*)(&sM[rr][k]);
      float4 hh = *(const float4*)(&sH[rr][k]);
#pragma unroll
      for (int c = 0; c < 3; ++c) {
        gi[c][rr] += wi[c].x * ms.x + wi[c].y * ms.y + wi[c].z * ms.z + wi[c].w * ms.w;
        gh[c][rr] += wh[c].x * hh.x + wh[c].y * hh.y + wh[c].z * hh.z + wh[c].w * hh.w;
      }
    }
  }
#pragma unroll
  for (int rr = 0; rr < 8; ++rr) {
    float r = sigm(gi[0][rr] + gh[0][rr]);
    float z = sigm(gi[1][rr] + gh[1][rr]);
    float n = tanhf(gi[2][rr] + r * gh[2][rr]);
    sHn[rr][tid] = (1.f - z) * n + z * sH[rr][tid];
  }
  __syncthreads();
  float lab[3][8];
  int cs[3]; bool has[3];
#pragma unroll
  for (int c = 0; c < 3; ++c) {
    cs[c] = tid + 256 * c;
    has[c] = cs[c] < CLSD;
    float b0 = has[c] ? br[cs[c]] : 0.f;
#pragma unroll
    for (int rr = 0; rr < 8; ++rr) lab[c][rr] = b0;
  }
  for (int k = 0; k < 256; k += 4) {
    float4 wr[3];
#pragma unroll
    for (int c = 0; c < 3; ++c) {
      if (has[c]) wr[c] = *(const float4*)(Wr + (size_t)cs[c] * 256 + k);
      else { wr[c].x = 0.f; wr[c].y = 0.f; wr[c].z = 0.f; wr[c].w = 0.f; }
    }
#pragma unroll
    for (int rr = 0; rr < 8; ++rr) {
      float4 hv = *(const float4*)(&sHn[rr][k]);
#pragma unroll
      for (int c = 0; c < 3; ++c)
        lab[c][rr] += wr[c].x * hv.x + wr[c].y * hv.y + wr[c].z * hv.z + wr[c].w * hv.w;
    }
  }
#pragma unroll
  for (int c = 0; c < 3; ++c) {
    if (has[c]) {
#pragma unroll
      for (int rr = 0; rr < 8; ++rr)
        outlab[(size_t)(r0 + rr) * CLSD + cs[c]] = lab[c][rr];
    }
  }
}

// ---------------------------------------------------------------- launch
extern "C" void kernel_launch(void* const* d_in, const int* in_sizes, int n_in,
                              void* d_out, int out_size, void* d_ws, size_t ws_size,
                              hipStream_t stream) {
  const float* edge = (const float*)d_in[0];
  const float* node = (const float*)d_in[1];
  const float* W_er = (const float*)d_in[6];
  const float* b_er = (const float*)d_in[7];
  const float* W_nr = (const float*)d_in[8];
  const float* b_nr = (const float*)d_in[9];
  const float* W_l1 = (const float*)d_in[10];
  const float* b_l1 = (const float*)d_in[11];
  const float* W_l2 = (const float*)d_in[12];
  const float* b_l2 = (const float*)d_in[13];
  const float* W_m  = (const float*)d_in[14];
  const float* b_m  = (const float*)d_in[15];
  const float* W_ih = (const float*)d_in[16];
  const float* b_ih = (const float*)d_in[17];
  const float* W_hh = (const float*)d_in[18];
  const float* b_hh = (const float*)d_in[19];
  const float* W_r  = (const float*)d_in[20];
  const float* b_r  = (const float*)d_in[21];

  char* ws = (char*)d_ws;
  size_t off = 0;
  auto alloc = [&](size_t bytes) -> void* {
    void* p = ws + off;
    off += (bytes + 511) & ~(size_t)511;
    return p;
  };
  u16* WerB     = (u16*)alloc((size_t)262144 * 2);
  u16* WmB      = (u16*)alloc((size_t)131072 * 2);
  u16* Wl1B     = (u16*)alloc((size_t)131072 * 2);
  u16* WcombB   = (u16*)alloc((size_t)262144 * 2);
  float* bcombF = (float*)alloc((size_t)256 * 4);
  u16* msghB    = (u16*)alloc((size_t)262144 * 2);
  float* h32    = (float*)alloc((size_t)262144 * 4);
  float* msum   = (float*)alloc((size_t)262144 * 4);
  u16* M0g      = (u16*)alloc((size_t)33554432 * 2);   // 64 MiB
  size_t off_m0 = off;
  const bool fast = (ws_size >= off_m0);
  u16* M0arg = fast ? M0g : (u16*)nullptr;

  float* out_pa  = (float*)d_out;
  float* out_lab = out_pa + 131072;

  k_cvt   <<<256,  256, 0, stream>>>(W_er, WerB, 262144);
  k_cvt   <<<128,  256, 0, stream>>>(W_m,  WmB,  131072);
  k_cvt   <<<128,  256, 0, stream>>>(W_l1, Wl1B, 131072);
  s1_hmsg2<<<1024, 256, 0, stream>>>(node, W_nr, b_nr, W_m, h32, msghB);
  if (!fast)
    k_comb<<<1024, 256, 0, stream>>>(W_m, W_er, b_er, b_m, WcombB, bcombF);

  k_main_full<<<2048, 256, 0, stream>>>(edge, WerB, WmB, Wl1B, b_er, b_m, b_l1, W_l2, b_l2,
                                        msghB, M0arg, out_pa);
  if (fast)
    k_msum_lite<<<1024, 256, 0, stream>>>(M0g, out_pa, msum);
  else
    k_msum2<<<1024, 256, 0, stream>>>(edge, WcombB, bcombF, msghB, out_pa, msum);
  k_gru<<<128, 256, 0, stream>>>(msum, h32, W_ih, b_ih, W_hh, b_hh, W_r, b_r, out_lab);
}

// Round 16
// 588.415 us; speedup vs baseline: 1.2510x; 1.0929x over previous
//
#include <hip/hip_runtime.h>
#include <cstdint>
#include <cstddef>

#define NND   128
#define FEATD 1024
#define MSGD  256
#define LHD   512
#define CLSD  600
#define LDST  264   // padded LDS row stride (528B, 16B-aligned)

typedef __bf16 bf16_t;
typedef bf16_t bf16x8 __attribute__((ext_vector_type(8)));
typedef float  f32x4  __attribute__((ext_vector_type(4)));
typedef unsigned short u16;
typedef u16 u16x8 __attribute__((ext_vector_type(8)));
typedef u16 u16x4 __attribute__((ext_vector_type(4)));

static __device__ __forceinline__ float bf2f(u16 u) {
  union { unsigned u; float f; } x; x.u = ((unsigned)u) << 16; return x.f;
}
static __device__ __forceinline__ u16 f2bf(float f) {
  union { float f; unsigned u; } x; x.f = f;
  return (u16)((x.u + 0x7fffu + ((x.u >> 16) & 1u)) >> 16);  // RNE
}
static __device__ __forceinline__ f32x4 mfma16(u16x8 a, u16x8 b, f32x4 c) {
  return __builtin_amdgcn_mfma_f32_16x16x32_bf16(
      __builtin_bit_cast(bf16x8, a), __builtin_bit_cast(bf16x8, b), c, 0, 0, 0);
}
static __device__ __forceinline__ f32x4 zero4() {
  f32x4 v; v[0] = 0.f; v[1] = 0.f; v[2] = 0.f; v[3] = 0.f; return v;
}
static __device__ __forceinline__ float sigm(float x) { return 1.0f / (1.0f + expf(-x)); }

// ---------------------------------------------------------------- all weight cvts in ONE kernel
// segments (1024-elem blocks): W_er 256 | W_m 128 | W_l1 128 | W_ih 192 | W_hh 192 | W_r 150  => grid 1046
__global__ __launch_bounds__(256) void k_cvt_all(
    const float* __restrict__ s0, const float* __restrict__ s1, const float* __restrict__ s2,
    const float* __restrict__ s3, const float* __restrict__ s4, const float* __restrict__ s5,
    u16* __restrict__ d0, u16* __restrict__ d1, u16* __restrict__ d2,
    u16* __restrict__ d3, u16* __restrict__ d4, u16* __restrict__ d5) {
  const int b = blockIdx.x;
  const float* src; u16* dst; int off;
  if (b < 256)      { src = s0; dst = d0; off = b; }
  else if (b < 384) { src = s1; dst = d1; off = b - 256; }
  else if (b < 512) { src = s2; dst = d2; off = b - 384; }
  else if (b < 704) { src = s3; dst = d3; off = b - 512; }
  else if (b < 896) { src = s4; dst = d4; off = b - 704; }
  else              { src = s5; dst = d5; off = b - 896; }
  const int i = off * 1024 + threadIdx.x * 4;
  float4 f = *(const float4*)(src + i);
  u16x4 o; o[0] = f2bf(f.x); o[1] = f2bf(f.y); o[2] = f2bf(f.z); o[3] = f2bf(f.w);
  *(u16x4*)(dst + i) = o;
}

// ---------------------------------------------------------------- W_comb (tier2 fallback only)
__global__ __launch_bounds__(256) void k_comb(const float* __restrict__ Wm,
                                              const float* __restrict__ Wer,
                                              const float* __restrict__ b_er,
                                              const float* __restrict__ b_m,
                                              u16* __restrict__ WcombB,
                                              float* __restrict__ bcomb) {
  const int m = blockIdx.x >> 2, ch = blockIdx.x & 3;
  const int d = ch * 256 + threadIdx.x;
  float s = 0.f;
  for (int k = 0; k < 256; ++k)
    s += Wm[(size_t)m * 512 + 256 + k] * Wer[(size_t)k * FEATD + d];
  WcombB[(size_t)m * FEATD + d] = f2bf(s);
  if (ch == 0 && threadIdx.x == 0) {
    float bb2 = b_m[m];
    for (int k = 0; k < 256; ++k) bb2 += Wm[(size_t)m * 512 + 256 + k] * b_er[k];
    bcomb[m] = bb2;
  }
}

// ---------------------------------------------------------------- S1 v3: 4 rows/block, wave-cooperative dots
__global__ __launch_bounds__(256) void s1_hmsg4(const float* __restrict__ node,
                                                const float* __restrict__ Wnr,
                                                const float* __restrict__ bnr,
                                                const float* __restrict__ Wm,
                                                float* __restrict__ h32,
                                                u16* __restrict__ msghB) {
  __shared__ __align__(16) float nrow[4][FEATD];
  __shared__ __align__(16) float hrow[4][MSGD];
  const int r0 = blockIdx.x * 4;              // 256 blocks x 4 rows
  const int tid = threadIdx.x, lane = tid & 63, wave = tid >> 6;
#pragma unroll
  for (int i = 0; i < 4; ++i)
    *(float4*)(&nrow[i][tid * 4]) = *(const float4*)(node + (size_t)(r0 + i) * FEATD + tid * 4);
  __syncthreads();
  // h: wave w owns cols [w*64, w*64+64); one Wnr row-read serves 4 row-dots
  for (int i = 0; i < 64; ++i) {
    const int col = wave * 64 + i;
    const float* wp = Wnr + (size_t)col * FEATD + lane * 16;
    float4 w[4];
#pragma unroll
    for (int j = 0; j < 4; ++j) w[j] = *(const float4*)(wp + j * 4);
    float s[4];
#pragma unroll
    for (int r = 0; r < 4; ++r) {
      const float* np = &nrow[r][lane * 16];
      float a = 0.f;
#pragma unroll
      for (int j = 0; j < 4; ++j) {
        float4 n4 = *(const float4*)(np + j * 4);
        a += w[j].x * n4.x + w[j].y * n4.y + w[j].z * n4.z + w[j].w * n4.w;
      }
      s[r] = a;
    }
#pragma unroll
    for (int off = 1; off < 64; off <<= 1)
#pragma unroll
      for (int r = 0; r < 4; ++r) s[r] += __shfl_xor(s[r], off, 64);
    if (lane == 0) {
      float be = bnr[col];
#pragma unroll
      for (int r = 0; r < 4; ++r) hrow[r][col] = s[r] + be;
    }
  }
  __syncthreads();
#pragma unroll
  for (int i = 0; i < 4; ++i) h32[(size_t)(r0 + i) * MSGD + tid] = hrow[i][tid];
  // msg_h: dot over 256 (Wm left half)
  for (int i = 0; i < 64; ++i) {
    const int col = wave * 64 + i;
    float4 w4 = *(const float4*)(Wm + (size_t)col * 512 + lane * 4);
    float s[4];
#pragma unroll
    for (int r = 0; r < 4; ++r) {
      float4 h4 = *(const float4*)(&hrow[r][lane * 4]);
      s[r] = w4.x * h4.x + w4.y * h4.y + w4.z * h4.z + w4.w * h4.w;
    }
#pragma unroll
    for (int off = 1; off < 64; off <<= 1)
#pragma unroll
      for (int r = 0; r < 4; ++r) s[r] += __shfl_xor(s[r], off, 64);
    if (lane == 0) {
#pragma unroll
      for (int r = 0; r < 4; ++r) msghB[(size_t)(r0 + r) * MSGD + col] = f2bf(s[r]);
    }
  }
}

// ---------------------------------------------------------------- main monolith — R11/R15 exact (443us best known)
__global__ __launch_bounds__(256, 2) void k_main_full(
    const float* __restrict__ edge, const u16* __restrict__ Wer, const u16* __restrict__ Wm,
    const u16* __restrict__ Wl1, const float* __restrict__ b_er, const float* __restrict__ b_m,
    const float* __restrict__ b_l1, const float* __restrict__ W_l2, const float* __restrict__ b_l2,
    const u16* __restrict__ msgh, u16* __restrict__ M0g, float* __restrict__ pa_out) {
  __shared__ __align__(16) u16 lsE[64][LDST];
  __shared__ __align__(16) u16 lsM[64][LDST];
  __shared__ float lsPA[4][64];
  __shared__ float lsSig[64];

  const int tid = threadIdx.x, lane = tid & 63, wave = tid >> 6;
  const int lh = lane & 15, lq = lane >> 4;
  const int base = blockIdx.x * 64;
  const int bb = base >> 14, vv = (base >> 7) & 127, w0 = base & 127;

  f32x4 acc[4][4];
#pragma unroll
  for (int m = 0; m < 4; ++m)
#pragma unroll
    for (int t = 0; t < 4; ++t) acc[m][t] = zero4();

  const int srow = tid >> 2;
  const int scq  = (tid & 3) * 16;
  const float* esrc = edge + (size_t)(base + srow) * FEATD + scq;
  float4 lda[4], ldb[4];
  u16x8 bst[2][4];

  auto LOADS_A = [&](int s) {
#pragma unroll
    for (int i = 0; i < 4; ++i) lda[i] = *(const float4*)(esrc + s * 64 + i * 4);
  };
  auto LOADS_B = [&](int s) {
#pragma unroll
    for (int i = 0; i < 4; ++i) ldb[i] = *(const float4*)(esrc + s * 64 + i * 4);
  };
  auto WRITES = [&](const float4* ld, int slot) {
    u16* wp = &lsE[srow][slot * 64 + scq];
    u16x8 o0, o1;
    o0[0] = f2bf(ld[0].x); o0[1] = f2bf(ld[0].y); o0[2] = f2bf(ld[0].z); o0[3] = f2bf(ld[0].w);
    o0[4] = f2bf(ld[1].x); o0[5] = f2bf(ld[1].y); o0[6] = f2bf(ld[1].z); o0[7] = f2bf(ld[1].w);
    o1[0] = f2bf(ld[2].x); o1[1] = f2bf(ld[2].y); o1[2] = f2bf(ld[2].z); o1[3] = f2bf(ld[2].w);
    o1[4] = f2bf(ld[3].x); o1[5] = f2bf(ld[3].y); o1[6] = f2bf(ld[3].z); o1[7] = f2bf(ld[3].w);
    *(u16x8*)wp = o0;
    *(u16x8*)(wp + 8) = o1;
  };
  auto BLOAD = [&](int sk) {
#pragma unroll
    for (int ks = 0; ks < 2; ++ks)
#pragma unroll
      for (int t = 0; t < 4; ++t) {
        int col = wave * 64 + t * 16 + lh;
        bst[ks][t] = *(const u16x8*)(Wer + (size_t)col * FEATD + sk * 64 + ks * 32 + lq * 8);
      }
  };
  auto MCOMP = [&](int slot) {
#pragma unroll
    for (int ks = 0; ks < 2; ++ks) {
      u16x8 afr[4];
#pragma unroll
      for (int m = 0; m < 4; ++m)
        afr[m] = *(const u16x8*)(&lsE[16 * m + lh][slot * 64 + ks * 32 + lq * 8]);
#pragma unroll
      for (int t = 0; t < 4; ++t)
#pragma unroll
        for (int m = 0; m < 4; ++m) acc[m][t] = mfma16(afr[m], bst[ks][t], acc[m][t]);
    }
  };

  LOADS_A(0);
  LOADS_B(1);
  for (int s2 = 0; s2 < 16; s2 += 2) {
    WRITES(lda, 0);
    if (s2 + 2 < 16) LOADS_A(s2 + 2);
    BLOAD(s2);
    __syncthreads();
    MCOMP(0);
    WRITES(ldb, 1);
    if (s2 + 3 < 16) LOADS_B(s2 + 3);
    BLOAD(s2 + 1);
    __syncthreads();
    MCOMP(1);
  }
  __syncthreads();
#pragma unroll
  for (int t = 0; t < 4; ++t) {
    int col = wave * 64 + t * 16 + lh;
    float be = b_er[col];
#pragma unroll
    for (int m = 0; m < 4; ++m)
#pragma unroll
      for (int j = 0; j < 4; ++j)
        lsE[16 * m + 4 * lq + j][col] = f2bf(acc[m][t][j] + be);
  }
  __syncthreads();

  // Phase A: sig1
  float prow[4][4];
#pragma unroll
  for (int m = 0; m < 4; ++m)
#pragma unroll
    for (int j = 0; j < 4; ++j) prow[m][j] = 0.f;
#pragma unroll
  for (int np = 0; np < 2; ++np) {
#pragma unroll
    for (int m = 0; m < 4; ++m)
#pragma unroll
      for (int t = 0; t < 4; ++t) acc[m][t] = zero4();
    u16x8 bcur[4];
#pragma unroll
    for (int t = 0; t < 4; ++t)
      bcur[t] = *(const u16x8*)(Wl1 + (size_t)(wave * 128 + np * 64 + t * 16 + lh) * MSGD + lq * 8);
#pragma unroll
    for (int ks = 0; ks < 8; ++ks) {
      u16x8 bnxt[4];
      if (ks < 7) {
#pragma unroll
        for (int t = 0; t < 4; ++t)
          bnxt[t] = *(const u16x8*)(Wl1 + (size_t)(wave * 128 + np * 64 + t * 16 + lh) * MSGD +
                                    (ks + 1) * 32 + lq * 8);
      }
      u16x8 afr[4];
#pragma unroll
      for (int m = 0; m < 4; ++m) afr[m] = *(const u16x8*)(&lsE[16 * m + lh][ks * 32 + lq * 8]);
#pragma unroll
      for (int t = 0; t < 4; ++t)
#pragma unroll
        for (int m = 0; m < 4; ++m) acc[m][t] = mfma16(afr[m], bcur[t], acc[m][t]);
      if (ks < 7) {
#pragma unroll
        for (int t = 0; t < 4; ++t) bcur[t] = bnxt[t];
      }
    }
#pragma unroll
    for (int t = 0; t < 4; ++t) {
      int col = wave * 128 + np * 64 + t * 16 + lh;
      float bl = b_l1[col], wl = W_l2[col];
#pragma unroll
      for (int m = 0; m < 4; ++m)
#pragma unroll
        for (int j = 0; j < 4; ++j) prow[m][j] += fmaxf(acc[m][t][j] + bl, 0.f) * wl;
    }
  }
#pragma unroll
  for (int off = 1; off < 16; off <<= 1)
#pragma unroll
    for (int m = 0; m < 4; ++m)
#pragma unroll
      for (int j = 0; j < 4; ++j) prow[m][j] += __shfl_xor(prow[m][j], off, 64);
  if (lh == 0) {
#pragma unroll
    for (int m = 0; m < 4; ++m)
#pragma unroll
      for (int j = 0; j < 4; ++j) lsPA[wave][16 * m + 4 * lq + j] = prow[m][j];
  }
  __syncthreads();
  if (tid < 64) {
    float pa1 = lsPA[0][tid] + lsPA[1][tid] + lsPA[2][tid] + lsPA[3][tid] + b_l2[0];
    lsSig[tid] = sigm(pa1);
  }
#pragma unroll
  for (int i = 0; i < 8; ++i) {
    int idx = tid + i * 256;
    int row = idx >> 5;
    int c8 = (idx & 31) << 3;
    *(u16x8*)(&lsM[row][c8]) =
        *(const u16x8*)(msgh + (size_t)(bb * NND + w0 + row) * MSGD + c8);
  }
  __syncthreads();

  // Phase B: M0
#pragma unroll
  for (int m = 0; m < 4; ++m)
#pragma unroll
    for (int t = 0; t < 4; ++t) acc[m][t] = zero4();
  {
    u16x8 bcur[4];
#pragma unroll
    for (int t = 0; t < 4; ++t)
      bcur[t] = *(const u16x8*)(Wm + (size_t)(wave * 64 + t * 16 + lh) * 512 + 256 + lq * 8);
#pragma unroll
    for (int ks = 0; ks < 8; ++ks) {
      u16x8 bnxt[4];
      if (ks < 7) {
#pragma unroll
        for (int t = 0; t < 4; ++t)
          bnxt[t] = *(const u16x8*)(Wm + (size_t)(wave * 64 + t * 16 + lh) * 512 + 256 +
                                    (ks + 1) * 32 + lq * 8);
      }
      u16x8 afr[4];
#pragma unroll
      for (int m = 0; m < 4; ++m) afr[m] = *(const u16x8*)(&lsE[16 * m + lh][ks * 32 + lq * 8]);
#pragma unroll
      for (int t = 0; t < 4; ++t)
#pragma unroll
        for (int m = 0; m < 4; ++m) acc[m][t] = mfma16(afr[m], bcur[t], acc[m][t]);
      if (ks < 7) {
#pragma unroll
        for (int t = 0; t < 4; ++t) bcur[t] = bnxt[t];
      }
    }
  }
#pragma unroll
  for (int t = 0; t < 4; ++t) {
    int col = wave * 64 + t * 16 + lh;
    float bm = b_m[col];
#pragma unroll
    for (int m = 0; m < 4; ++m)
#pragma unroll
      for (int j = 0; j < 4; ++j) {
        int row = 16 * m + 4 * lq + j;
        float mh = bf2f(lsM[row][col]);
        lsM[row][col] = f2bf(fmaxf(acc[m][t][j] + bm + mh, 0.f));
      }
  }
  __syncthreads();
#pragma unroll
  for (int i = 0; i < 8; ++i) {
    int idx = tid + i * 256;
    int row = idx >> 5;
    int c8 = (idx & 31) << 3;
    u16x8 m0v = *(const u16x8*)(&lsM[row][c8]);
    if (M0g) *(u16x8*)(M0g + (size_t)(base + row) * MSGD + c8) = m0v;
    float s = lsSig[row];
    u16x8 sc;
#pragma unroll
    for (int j = 0; j < 8; ++j) sc[j] = f2bf(bf2f(m0v[j]) * s);
    *(u16x8*)(&lsM[row][c8]) = sc;
  }
  __syncthreads();

  // Phase C: pred_adj2 scatter-T
#pragma unroll
  for (int m = 0; m < 4; ++m)
#pragma unroll
    for (int j = 0; j < 4; ++j) prow[m][j] = 0.f;
#pragma unroll
  for (int np = 0; np < 2; ++np) {
#pragma unroll
    for (int m = 0; m < 4; ++m)
#pragma unroll
      for (int t = 0; t < 4; ++t) acc[m][t] = zero4();
    u16x8 bcur[4];
#pragma unroll
    for (int t = 0; t < 4; ++t)
      bcur[t] = *(const u16x8*)(Wl1 + (size_t)(wave * 128 + np * 64 + t * 16 + lh) * MSGD + lq * 8);
#pragma unroll
    for (int ks = 0; ks < 8; ++ks) {
      u16x8 bnxt[4];
      if (ks < 7) {
#pragma unroll
        for (int t = 0; t < 4; ++t)
          bnxt[t] = *(const u16x8*)(Wl1 + (size_t)(wave * 128 + np * 64 + t * 16 + lh) * MSGD +
                                    (ks + 1) * 32 + lq * 8);
      }
      u16x8 afr[4];
#pragma unroll
      for (int m = 0; m < 4; ++m) afr[m] = *(const u16x8*)(&lsM[16 * m + lh][ks * 32 + lq * 8]);
#pragma unroll
      for (int t = 0; t < 4; ++t)
#pragma unroll
        for (int m = 0; m < 4; ++m) acc[m][t] = mfma16(afr[m], bcur[t], acc[m][t]);
      if (ks < 7) {
#pragma unroll
        for (int t = 0; t < 4; ++t) bcur[t] = bnxt[t];
      }
    }
#pragma unroll
    for (int t = 0; t < 4; ++t) {
      int col = wave * 128 + np * 64 + t * 16 + lh;
      float bl = b_l1[col], wl = W_l2[col];
#pragma unroll
      for (int m = 0; m < 4; ++m)
#pragma unroll
        for (int j = 0; j < 4; ++j) prow[m][j] += fmaxf(acc[m][t][j] + bl, 0.f) * wl;
    }
  }
#pragma unroll
  for (int off = 1; off < 16; off <<= 1)
#pragma unroll
    for (int m = 0; m < 4; ++m)
#pragma unroll
      for (int j = 0; j < 4; ++j) prow[m][j] += __shfl_xor(prow[m][j], off, 64);
  if (lh == 0) {
#pragma unroll
    for (int m = 0; m < 4; ++m)
#pragma unroll
      for (int j = 0; j < 4; ++j) lsPA[wave][16 * m + 4 * lq + j] = prow[m][j];
  }
  __syncthreads();
  if (tid < 64) {
    float q = lsPA[0][tid] + lsPA[1][tid] + lsPA[2][tid] + lsPA[3][tid] + b_l2[0];
    size_t o = ((size_t)bb * NND + (w0 + tid)) * NND + vv;
    pa_out[o] = q;
  }
}

// ---------------------------------------------------------------- m_sum from stored M0 (coalesced)
__global__ __launch_bounds__(256) void k_msum_lite(const u16* __restrict__ M0g,
                                                   const float* __restrict__ qv,
                                                   float* __restrict__ msum) {
  __shared__ float sig[128];
  __shared__ __align__(16) float part[8][256];
  const int bv = blockIdx.x, tid = threadIdx.x;
  if (tid < 128) sig[tid] = sigm(qv[(size_t)bv * NND + tid]);
  __syncthreads();
  const int cg = (tid & 31) * 8, rg = tid >> 5;
  float a[8];
#pragma unroll
  for (int j = 0; j < 8; ++j) a[j] = 0.f;
  for (int i = 0; i < 16; ++i) {
    int row = rg + i * 8;
    u16x8 v = *(const u16x8*)(M0g + ((size_t)bv * NND + row) * MSGD + cg);
    float s = sig[row];
#pragma unroll
    for (int j = 0; j < 8; ++j) a[j] += s * bf2f(v[j]);
  }
#pragma unroll
  for (int j = 0; j < 8; ++j) part[rg][cg + j] = a[j];
  __syncthreads();
  float r = 0.f;
#pragma unroll
  for (int g = 0; g < 8; ++g) r += part[g][tid];
  msum[(size_t)bv * MSGD + tid] = r;
}

// ---------------------------------------------------------------- tier2 m_sum: recompute via W_comb
__global__ __launch_bounds__(256, 2) void k_msum2(
    const float* __restrict__ edge, const u16* __restrict__ Wcomb,
    const float* __restrict__ bcomb, const u16* __restrict__ msgh,
    const float* __restrict__ qv, float* __restrict__ msum) {
  __shared__ __align__(16) u16 lsE[64][LDST];
  __shared__ __align__(16) u16 lsM[64][LDST];
  __shared__ float lsSig[64];
  const int tid = threadIdx.x, lane = tid & 63, wave = tid >> 6;
  const int lh = lane & 15, lq = lane >> 4;
  const int bv = blockIdx.x;
  const int bb = bv >> 7;

  float csum[4] = {0.f, 0.f, 0.f, 0.f};

  for (int hh = 0; hh < 2; ++hh) {
    if (tid < 64) lsSig[tid] = sigm(qv[(size_t)bv * NND + hh * 64 + tid]);
#pragma unroll
    for (int i = 0; i < 8; ++i) {
      int idx = tid + i * 256;
      int row = idx >> 5;
      int c8 = (idx & 31) << 3;
      *(u16x8*)(&lsM[row][c8]) =
          *(const u16x8*)(msgh + (size_t)(bb * NND + hh * 64 + row) * MSGD + c8);
    }
    f32x4 acc[4][4];
#pragma unroll
    for (int m = 0; m < 4; ++m)
#pragma unroll
      for (int t = 0; t < 4; ++t) acc[m][t] = zero4();

    for (int kc = 0; kc < 4; ++kc) {
#pragma unroll
      for (int i = 0; i < 16; ++i) {
        int idx = tid + i * 256;
        int row = idx >> 6;
        int c4 = (idx & 63) << 2;
        float4 f = *(const float4*)(edge + (size_t)(bv * NND + hh * 64 + row) * FEATD + kc * 256 + c4);
        u16x4 o; o[0] = f2bf(f.x); o[1] = f2bf(f.y); o[2] = f2bf(f.z); o[3] = f2bf(f.w);
        *(u16x4*)(&lsE[row][c4]) = o;
      }
      __syncthreads();
#pragma unroll
      for (int ks = 0; ks < 8; ++ks) {
        u16x8 afr[4];
#pragma unroll
        for (int m = 0; m < 4; ++m) afr[m] = *(const u16x8*)(&lsE[16 * m + lh][ks * 32 + lq * 8]);
        const int kg = kc * 256 + ks * 32 + lq * 8;
#pragma unroll
        for (int t = 0; t < 4; ++t) {
          int col = wave * 64 + t * 16 + lh;
          u16x8 bfr = *(const u16x8*)(Wcomb + (size_t)col * FEATD + kg);
#pragma unroll
          for (int m = 0; m < 4; ++m) acc[m][t] = mfma16(afr[m], bfr, acc[m][t]);
        }
      }
      __syncthreads();
    }
#pragma unroll
    for (int t = 0; t < 4; ++t) {
      int col = wave * 64 + t * 16 + lh;
      float bc = bcomb[col];
#pragma unroll
      for (int m = 0; m < 4; ++m)
#pragma unroll
        for (int j = 0; j < 4; ++j) {
          int row = 16 * m + 4 * lq + j;
          float m0 = fmaxf(acc[m][t][j] + bc + bf2f(lsM[row][col]), 0.f);
          csum[t] += lsSig[row] * m0;
        }
    }
    __syncthreads();
  }
#pragma unroll
  for (int off = 16; off < 64; off <<= 1)
#pragma unroll
    for (int t = 0; t < 4; ++t) csum[t] += __shfl_xor(csum[t], off, 64);
  if (lq == 0) {
#pragma unroll
    for (int t = 0; t < 4; ++t)
      msum[(size_t)bv * MSGD + wave * 64 + t * 16 + lh] = csum[t];
  }
}

// ---------------------------------------------------------------- GRU + labels (8 rows/block, bf16 weights, f32 biases)
__global__ __launch_bounds__(256) void k_gru_bf(const float* __restrict__ msum,
                                                const float* __restrict__ h32,
                                                const u16* __restrict__ Wih, const float* __restrict__ bih,
                                                const u16* __restrict__ Whh, const float* __restrict__ bhh,
                                                const u16* __restrict__ Wr, const float* __restrict__ br,
                                                float* __restrict__ outlab) {
  __shared__ __align__(16) float sM[8][256];
  __shared__ __align__(16) float sH[8][256];
  __shared__ __align__(16) float sHn[8][256];
  const int tid = threadIdx.x;
  const int r0 = blockIdx.x * 8;
#pragma unroll
  for (int i = 0; i < 2; ++i) {
    int idx = tid + i * 256;
    int row = idx >> 6;
    int c = (idx & 63) << 2;
    *(float4*)(&sM[row][c]) = *(const float4*)(msum + (size_t)(r0 + row) * 256 + c);
    *(float4*)(&sH[row][c]) = *(const float4*)(h32 + (size_t)(r0 + row) * 256 + c);
  }
  __syncthreads();
  float gi[3][8], gh[3][8];
#pragma unroll
  for (int c = 0; c < 3; ++c) {
    float bi_ = bih[tid + 256 * c], bh_ = bhh[tid + 256 * c];
#pragma unroll
    for (int rr = 0; rr < 8; ++rr) { gi[c][rr] = bi_; gh[c][rr] = bh_; }
  }
  for (int k = 0; k < 256; k += 8) {
    u16x8 wi[3], wh[3];
#pragma unroll
    for (int c = 0; c < 3; ++c) {
      wi[c] = *(const u16x8*)(Wih + (size_t)(tid + 256 * c) * 256 + k);
      wh[c] = *(const u16x8*)(Whh + (size_t)(tid + 256 * c) * 256 + k);
    }
#pragma unroll
    for (int j = 0; j < 8; ++j) {
      float wif0 = bf2f(wi[0][j]), wif1 = bf2f(wi[1][j]), wif2 = bf2f(wi[2][j]);
      float whf0 = bf2f(wh[0][j]), whf1 = bf2f(wh[1][j]), whf2 = bf2f(wh[2][j]);
#pragma unroll
      for (int rr = 0; rr < 8; ++rr) {
        float ms = sM[rr][k + j], hh = sH[rr][k + j];
        gi[0][rr] += wif0 * ms; gi[1][rr] += wif1 * ms; gi[2][rr] += wif2 * ms;
        gh[0][rr] += whf0 * hh; gh[1][rr] += whf1 * hh; gh[2][rr] += whf2 * hh;
      }
    }
  }
#pragma unroll
  for (int rr = 0; rr < 8; ++rr) {
    float r = sigm(gi[0][rr] + gh[0][rr]);
    float z = sigm(gi[1][rr] + gh[1][rr]);
    float n = tanhf(gi[2][rr] + r * gh[2][rr]);
    sHn[rr][tid] = (1.f - z) * n + z * sH[rr][tid];
  }
  __syncthreads();
  float lab[3][8];
  int cs[3]; bool has[3];
#pragma unroll
  for (int c = 0; c < 3; ++c) {
    cs[c] = tid + 256 * c;
    has[c] = cs[c] < CLSD;
    float b0 = has[c] ? br[cs[c]] : 0.f;
#pragma unroll
    for (int rr = 0; rr < 8; ++rr) lab[c][rr] = b0;
  }
  u16x8 zv;
#pragma unroll
  for (int j = 0; j < 8; ++j) zv[j] = 0;
  for (int k = 0; k < 256; k += 8) {
    u16x8 wr[3];
#pragma unroll
    for (int c = 0; c < 3; ++c)
      wr[c] = has[c] ? *(const u16x8*)(Wr + (size_t)cs[c] * 256 + k) : zv;
#pragma unroll
    for (int j = 0; j < 8; ++j) {
      float w0 = bf2f(wr[0][j]), w1 = bf2f(wr[1][j]), w2 = bf2f(wr[2][j]);
#pragma unroll
      for (int rr = 0; rr < 8; ++rr) {
        float hv = sHn[rr][k + j];
        lab[0][rr] += w0 * hv; lab[1][rr] += w1 * hv; lab[2][rr] += w2 * hv;
      }
    }
  }
#pragma unroll
  for (int c = 0; c < 3; ++c) {
    if (has[c]) {
#pragma unroll
      for (int rr = 0; rr < 8; ++rr)
        outlab[(size_t)(r0 + rr) * CLSD + cs[c]] = lab[c][rr];
    }
  }
}

// ---------------------------------------------------------------- launch
extern "C" void kernel_launch(void* const* d_in, const int* in_sizes, int n_in,
                              void* d_out, int out_size, void* d_ws, size_t ws_size,
                              hipStream_t stream) {
  const float* edge = (const float*)d_in[0];
  const float* node = (const float*)d_in[1];
  const float* W_er = (const float*)d_in[6];
  const float* b_er = (const float*)d_in[7];
  const float* W_nr = (const float*)d_in[8];
  const float* b_nr = (const float*)d_in[9];
  const float* W_l1 = (const float*)d_in[10];
  const float* b_l1 = (const float*)d_in[11];
  const float* W_l2 = (const float*)d_in[12];
  const float* b_l2 = (const float*)d_in[13];
  const float* W_m  = (const float*)d_in[14];
  const float* b_m  = (const float*)d_in[15];
  const float* W_ih = (const float*)d_in[16];
  const float* b_ih = (const float*)d_in[17];
  const float* W_hh = (const float*)d_in[18];
  const float* b_hh = (const float*)d_in[19];
  const float* W_r  = (const float*)d_in[20];
  const float* b_r  = (const float*)d_in[21];

  char* ws = (char*)d_ws;
  size_t off = 0;
  auto alloc = [&](size_t bytes) -> void* {
    void* p = ws + off;
    off += (bytes + 511) & ~(size_t)511;
    return p;
  };
  u16* WerB     = (u16*)alloc((size_t)262144 * 2);
  u16* WmB      = (u16*)alloc((size_t)131072 * 2);
  u16* Wl1B     = (u16*)alloc((size_t)131072 * 2);
  u16* WihB     = (u16*)alloc((size_t)196608 * 2);
  u16* WhhB     = (u16*)alloc((size_t)196608 * 2);
  u16* WrB      = (u16*)alloc((size_t)153600 * 2);
  u16* WcombB   = (u16*)alloc((size_t)262144 * 2);
  float* bcombF = (float*)alloc((size_t)256 * 4);
  u16* msghB    = (u16*)alloc((size_t)262144 * 2);
  float* h32    = (float*)alloc((size_t)262144 * 4);
  float* msum   = (float*)alloc((size_t)262144 * 4);
  u16* M0g      = (u16*)alloc((size_t)33554432 * 2);   // 64 MiB
  size_t off_m0 = off;
  const bool fast = (ws_size >= off_m0);
  u16* M0arg = fast ? M0g : (u16*)nullptr;

  float* out_pa  = (float*)d_out;
  float* out_lab = out_pa + 131072;

  k_cvt_all<<<1046, 256, 0, stream>>>(W_er, W_m, W_l1, W_ih, W_hh, W_r,
                                      WerB, WmB, Wl1B, WihB, WhhB, WrB);
  s1_hmsg4<<<256, 256, 0, stream>>>(node, W_nr, b_nr, W_m, h32, msghB);
  if (!fast)
    k_comb<<<1024, 256, 0, stream>>>(W_m, W_er, b_er, b_m, WcombB, bcombF);

  k_main_full<<<2048, 256, 0, stream>>>(edge, WerB, WmB, Wl1B, b_er, b_m, b_l1, W_l2, b_l2,
                                        msghB, M0arg, out_pa);
  if (fast)
    k_msum_lite<<<1024, 256, 0, stream>>>(M0g, out_pa, msum);
  else
    k_msum2<<<1024, 256, 0, stream>>>(edge, WcombB, bcombF, msghB, out_pa, msum);
  k_gru_bf<<<128, 256, 0, stream>>>(msum, h32, WihB, b_ih, WhhB, b_hh, WrB, b_r, out_lab);
}